// Round 5
// baseline (100.673 us; speedup 1.0000x reference)
//
#include <hip/hip_runtime.h>
#include <math.h>

#define NN 4096
#define KTOP 20
#define EPSF 1e-6f

// ---------------- block sum over 256 threads (4 waves) ----------------
__device__ __forceinline__ float block_rsumf(float v, volatile float* red) {
#pragma unroll
  for (int o = 1; o < 64; o <<= 1) v += __shfl_xor(v, o, 64);
  __syncthreads();
  if ((threadIdx.x & 63) == 0) red[threadIdx.x >> 6] = v;
  __syncthreads();
  return red[0] + red[1] + red[2] + red[3];
}

// ---------------- K0a: partial sums over bt chunks (deterministic) ----------------
__global__ __launch_bounds__(256) void k_prep_a(const float* __restrict__ xh,
    const float* __restrict__ ev, float* __restrict__ psx,
    float* __restrict__ psy, float* __restrict__ pse, int* __restrict__ cnt) {
  if (blockIdx.x == 0 && threadIdx.x == 0) *cnt = 0;
  int ic = blockIdx.x & 15, tc = blockIdx.x >> 4;
  int i = ic * 256 + threadIdx.x;
  const float2* xh2 = (const float2*)xh;
  float sx = 0.f, sy = 0.f, se = 0.f;
  for (int bt = tc * 24; bt < tc * 24 + 24; ++bt) {
    float2 v = xh2[(size_t)bt * NN + i];
    sx += v.x; sy += v.y;
    se += ev[(size_t)bt * NN + i];
  }
  psx[tc * NN + i] = sx; psy[tc * NN + i] = sy; pse[tc * NN + i] = se;
}

// ---------------- K0b: finalize featn / sev / impacted count ----------------
__global__ void k_prep_b(const float* __restrict__ psx, const float* __restrict__ psy,
    const float* __restrict__ pse, float2* __restrict__ featn,
    float* __restrict__ sev, int* __restrict__ cnt) {
  int i = blockIdx.x * 256 + threadIdx.x;
  float sx = 0.f, sy = 0.f, se = 0.f;
#pragma unroll
  for (int t = 0; t < 8; ++t) {
    sx += psx[t * NN + i]; sy += psy[t * NN + i]; se += pse[t * NN + i];
  }
  sx *= (1.f / 192.f); sy *= (1.f / 192.f); se *= (1.f / 192.f);
  float nrm = sqrtf(sx * sx + sy * sy) + EPSF;
  featn[i] = make_float2(sx / nrm, sy / nrm);
  sev[i] = se;
  unsigned long long m = __ballot(se > 0.f);
  if ((threadIdx.x & 63) == 0) atomicAdd(cnt, (int)__popcll(m));
}

// ---------------- K1: adaptive logits -> exp(relu(.)), float4 ----------------
__global__ __launch_bounds__(256) void k_gemm(const float* __restrict__ nv1,
    const float* __restrict__ nv2, float* __restrict__ aexp) {
  int jt = (blockIdx.x * 256 + threadIdx.x) * 4;
  int i0 = blockIdx.y * 64;
  float4 w[10];
#pragma unroll
  for (int d = 0; d < 10; ++d) w[d] = *(const float4*)&nv2[d * NN + jt];
  for (int it = 0; it < 64; ++it) {
    int i = i0 + it;
    const float* r = nv1 + (size_t)i * 10;  // uniform -> scalar loads
    float4 a = make_float4(0.f, 0.f, 0.f, 0.f);
#pragma unroll
    for (int d = 0; d < 10; ++d) {
      float rd = r[d];
      a.x += rd * w[d].x; a.y += rd * w[d].y;
      a.z += rd * w[d].z; a.w += rd * w[d].w;
    }
    float4 o;
    o.x = __expf(fmaxf(a.x, 0.f)); o.y = __expf(fmaxf(a.y, 0.f));
    o.z = __expf(fmaxf(a.z, 0.f)); o.w = __expf(fmaxf(a.w, 0.f));
    *(float4*)&aexp[(size_t)i * NN + jt] = o;
  }
}

// ---------------- block-wide exact fallback select (rare) ----------------
__device__ void fb_row(int i, const float (&v)[16], int* kidx, float* kval,
                       float* dinv, volatile float* redf, volatile int* redi,
                       int* eq_js, int* eq_cnt, int* slot) {
  const int tid = threadIdx.x;
  const int lane = tid & 63, wv = tid >> 6;
  unsigned cur = 0;
  for (int bit = 30; bit >= 0; --bit) {
    float tf = __uint_as_float(cur | (1u << bit));
    int lc = 0;
#pragma unroll
    for (int c = 0; c < 16; ++c) lc += (v[c] >= tf) ? 1 : 0;
#pragma unroll
    for (int o = 1; o < 64; o <<= 1) lc += __shfl_xor(lc, o, 64);
    __syncthreads();
    if (lane == 0) redi[wv] = lc;
    __syncthreads();
    int tot = redi[0] + redi[1] + redi[2] + redi[3];
    if (tot >= KTOP) cur |= (1u << bit);
  }
  float T = __uint_as_float(cur);
  int lgt = 0;
#pragma unroll
  for (int c = 0; c < 16; ++c) lgt += (v[c] > T) ? 1 : 0;
#pragma unroll
  for (int o = 1; o < 64; o <<= 1) lgt += __shfl_xor(lgt, o, 64);
  __syncthreads();
  if (lane == 0) redi[wv] = lgt;
  if (tid == 0) *eq_cnt = 0;
  __syncthreads();
  int cgt = redi[0] + redi[1] + redi[2] + redi[3];

  float lsum = 0.f;
#pragma unroll
  for (int c = 0; c < 16; ++c) {
    if (v[c] > T) {
      int p = atomicAdd(slot, 1);
      kidx[i * KTOP + p] = tid * 16 + c;
      kval[i * KTOP + p] = v[c];
      lsum += v[c];
    } else if (v[c] == T) {
      int p = atomicAdd(eq_cnt, 1);
      if (p < 64) eq_js[p] = tid * 16 + c;
    }
  }
  __syncthreads();
  int need = KTOP - cgt;
  if (tid == 0) {
    int m = *eq_cnt < 64 ? *eq_cnt : 64;
    for (int s = 0; s < need; ++s) {
      int best = s;
      for (int u = s + 1; u < m; ++u)
        if (eq_js[u] < eq_js[best]) best = u;
      int tmp = eq_js[s]; eq_js[s] = eq_js[best]; eq_js[best] = tmp;
      kidx[i * KTOP + cgt + s] = eq_js[s];
      kval[i * KTOP + cgt + s] = T;
    }
  }
  float tot = block_rsumf(lsum, redf);
  if (tid == 0) dinv[i] = 1.f / sqrtf(tot + (float)need * T + 1.f + EPSF);
}

// ---------------- K2: lean per-row fuse + exact top-k (float4 IO) ----------------
__global__ __launch_bounds__(256) void k_row(
    const float* __restrict__ base_adj, const float* __restrict__ aexp,
    const float2* __restrict__ featn, const float* __restrict__ sev,
    const float* __restrict__ alpha, const int* __restrict__ cnt,
    int* __restrict__ kidx, float* __restrict__ kval, float* __restrict__ dinv) {
  const int i = blockIdx.x;
  const int tid = threadIdx.x;
  const int lane = tid & 63, wv = tid >> 6;
  const int j0 = tid * 16;

  __shared__ float maxima[256];
  __shared__ float candV[64];
  __shared__ int candJ[64];
  __shared__ float redf[12];
  __shared__ int redi[4];
  __shared__ int eq_js[64];
  __shared__ int ccnt, wslot, eq_cnt;
  __shared__ float sTT;

  float2 fi = featn[i];
  float esc = sev[i] * 0.6065306597f;  // sev_i * exp(-0.5)
  float gamma = 1.f / (1.f + __expf(-alpha[0]));

  // ---- pass 1: vector loads + sums hs, as, ed ----
  const float4* b4 = (const float4*)(base_adj + (size_t)i * NN + j0);
  const float4* a4 = (const float4*)(aexp + (size_t)i * NN + j0);
  const float4* f4 = (const float4*)featn;  // 2 nodes per float4

  float b[16], ae[16];
  float hs = 0.f, as = 0.f, ed = 0.f;
#pragma unroll
  for (int q = 0; q < 4; ++q) {
    float4 B = b4[q], A = a4[q];
    b[q * 4 + 0] = B.x; b[q * 4 + 1] = B.y; b[q * 4 + 2] = B.z; b[q * 4 + 3] = B.w;
    ae[q * 4 + 0] = A.x; ae[q * 4 + 1] = A.y; ae[q * 4 + 2] = A.z; ae[q * 4 + 3] = A.w;
    as += A.x + A.y + A.z + A.w;
  }
#pragma unroll
  for (int p = 0; p < 8; ++p) {
    float4 fp = f4[tid * 8 + p];
    hs += __expf(fmaxf(fi.x * fp.x + fi.y * fp.y, 0.f)) +
          __expf(fmaxf(fi.x * fp.z + fi.y * fp.w, 0.f));
  }
  if (esc > 0.f) {
#pragma unroll
    for (int c = 0; c < 16; ++c)
      if (b[c] > 0.f) ed += __expf(esc * b[c]) - 1.f;
  }

  // fused 3-sum block reduction
#pragma unroll
  for (int o = 1; o < 64; o <<= 1) {
    hs += __shfl_xor(hs, o, 64);
    as += __shfl_xor(as, o, 64);
    ed += __shfl_xor(ed, o, 64);
  }
  if (lane == 0) { redf[wv * 3] = hs; redf[wv * 3 + 1] = as; redf[wv * 3 + 2] = ed; }
  __syncthreads();
  float HS = redf[0] + redf[3] + redf[6] + redf[9];
  float AS = redf[1] + redf[4] + redf[7] + redf[10];
  float ES = 4096.f + redf[2] + redf[5] + redf[8] + redf[11];

  float eflag = (*cnt > 0) ? 1.f : 0.f;
  float wh = 0.5f * gamma / HS;
  float we = 0.5f * (1.f - gamma) * eflag / ES;
  float wa = 0.5f / AS;

  // ---- pass 2: v values + thread max (featn L1-hot) ----
  float v[16];
  float m = 0.f;
#pragma unroll
  for (int p = 0; p < 8; ++p) {
    float4 fp = f4[tid * 8 + p];
    float he0 = __expf(fmaxf(fi.x * fp.x + fi.y * fp.y, 0.f));
    float he1 = __expf(fmaxf(fi.x * fp.z + fi.y * fp.w, 0.f));
    int c0 = 2 * p, c1 = 2 * p + 1;
    float v0 = wh * he0 + wa * ae[c0] + we;
    float v1 = wh * he1 + wa * ae[c1] + we;
    if (b[c0] > 0.f) {
      float add = 0.5f * b[c0];
      if (esc > 0.f) add += we * (__expf(esc * b[c0]) - 1.f);
      v0 += add;
    }
    if (b[c1] > 0.f) {
      float add = 0.5f * b[c1];
      if (esc > 0.f) add += we * (__expf(esc * b[c1]) - 1.f);
      v1 += add;
    }
    v[c0] = v0; v[c1] = v1;
    m = fmaxf(m, fmaxf(v0, v1));
  }
  maxima[tid] = m;
  if (tid == 0) { ccnt = 0; wslot = 0; }
  __syncthreads();

  // ---- threshold from 256 thread-maxima (12-bit prefix search, wave 0) ----
  if (wv == 0) {
    float x0 = maxima[lane], x1 = maxima[lane + 64];
    float x2 = maxima[lane + 128], x3 = maxima[lane + 192];
    unsigned cur = 0;
    for (int bit = 30; bit >= 19; --bit) {
      float tf = __uint_as_float(cur | (1u << bit));
      int c_ = __popcll(__ballot(x0 >= tf)) + __popcll(__ballot(x1 >= tf)) +
               __popcll(__ballot(x2 >= tf)) + __popcll(__ballot(x3 >= tf));
      if (c_ >= KTOP) cur |= (1u << bit);
    }
    sTT = __uint_as_float(cur);
  }
  __syncthreads();
  float T0 = sTT;

  // ---- collect candidates ----
#pragma unroll
  for (int c = 0; c < 16; ++c) {
    if (v[c] >= T0) {
      int p = atomicAdd(&ccnt, 1);
      if (p < 64) { candV[p] = v[c]; candJ[p] = j0 + c; }
    }
  }
  __syncthreads();
  bool fb = (ccnt > 64);

  // ---- wave-local exact top-20 among candidates ----
  if (!fb && wv == 0) {
    int n = ccnt;
    float lv = (lane < n) ? candV[lane] : 0.f;
    int lj = (lane < n) ? candJ[lane] : 0x7FFFFFFF;
    unsigned cur = 0;
    for (int bit = 30; bit >= 0; --bit) {
      float tf = __uint_as_float(cur | (1u << bit));
      if (__popcll(__ballot(lv >= tf)) >= KTOP) cur |= (1u << bit);
    }
    float T = __uint_as_float(cur);
    bool gt = lv > T;
    int cgt = __popcll(__ballot(gt));
    if (gt) {
      int p = atomicAdd(&wslot, 1);
      kidx[i * KTOP + p] = lj;
      kval[i * KTOP + p] = lv;
    }
    int need = KTOP - cgt;
    bool eq = (lv == T);
    for (int k = 0; k < need; ++k) {
      int pj = eq ? lj : 0x7FFFFFFF;
#pragma unroll
      for (int o = 1; o < 64; o <<= 1) {
        int q = __shfl_xor(pj, o, 64);
        pj = q < pj ? q : pj;
      }
      if (lane == 0) {
        kidx[i * KTOP + cgt + k] = pj;
        kval[i * KTOP + cgt + k] = T;
      }
      if (lj == pj) eq = false;
    }
    float ds = gt ? lv : 0.f;
#pragma unroll
    for (int o = 1; o < 64; o <<= 1) ds += __shfl_xor(ds, o, 64);
    if (lane == 0) dinv[i] = 1.f / sqrtf(ds + (float)need * T + 1.f + EPSF);
  }

  // ---- rare fallback ----
  if (fb) {
    __syncthreads();
    fb_row(i, v, kidx, kval, dinv, redf, redi, eq_js, &eq_cnt, &wslot);
  }
}

// ---------------- K3: write normalized sparse output (LDS row stage) ----------------
__global__ __launch_bounds__(256) void k_write(
    const int* __restrict__ kidx, const float* __restrict__ kval,
    const float* __restrict__ dinv, float* __restrict__ out) {
  const int i = blockIdx.x;
  const int tid = threadIdx.x;
  __shared__ float row[NN];
  float4* r4 = (float4*)row;
#pragma unroll
  for (int c = 0; c < 4; ++c) r4[c * 256 + tid] = make_float4(0.f, 0.f, 0.f, 0.f);
  __syncthreads();
  if (tid < KTOP) {
    int j = kidx[i * KTOP + tid];
    row[j] = kval[i * KTOP + tid];
  }
  __syncthreads();
  float di = dinv[i];
  const float4* dv4 = (const float4*)dinv;
  float4* o4 = (float4*)out;
#pragma unroll
  for (int c = 0; c < 4; ++c) {
    int j4 = c * 256 + tid;
    float4 rv = r4[j4];
    float4 dv = dv4[j4];
    int jb = j4 * 4;
    float4 o;
    o.x = di * (rv.x + ((jb + 0) == i ? 1.f : 0.f)) * dv.x;
    o.y = di * (rv.y + ((jb + 1) == i ? 1.f : 0.f)) * dv.y;
    o.z = di * (rv.z + ((jb + 2) == i ? 1.f : 0.f)) * dv.z;
    o.w = di * (rv.w + ((jb + 3) == i ? 1.f : 0.f)) * dv.w;
    o4[(size_t)i * (NN / 4) + j4] = o;
  }
}

extern "C" void kernel_launch(void* const* d_in, const int* in_sizes, int n_in,
                              void* d_out, int out_size, void* d_ws, size_t ws_size,
                              hipStream_t stream) {
  const float* xh    = (const float*)d_in[0];
  const float* ev    = (const float*)d_in[1];
  const float* base  = (const float*)d_in[2];
  const float* nv1   = (const float*)d_in[3];
  const float* nv2   = (const float*)d_in[4];
  const float* alpha = (const float*)d_in[5];
  float* out = (float*)d_out;

  char* ws = (char*)d_ws;
  int*    cnt   = (int*)ws;                 // 4 B (pad 256)
  float2* featn = (float2*)(ws + 256);      // 32 KB
  float*  sev   = (float*)(ws + 33024);     // 16 KB
  float*  dinv  = (float*)(ws + 49408);     // 16 KB
  int*    kidx  = (int*)(ws + 65792);       // 320 KB
  float*  kval  = (float*)(ws + 393472);    // 320 KB
  float*  psx   = (float*)(ws + 721152);    // 128 KB
  float*  psy   = (float*)(ws + 852224);    // 128 KB
  float*  pse   = (float*)(ws + 983296);    // 128 KB

  k_prep_a<<<128, 256, 0, stream>>>(xh, ev, psx, psy, pse, cnt);
  k_prep_b<<<16, 256, 0, stream>>>(psx, psy, pse, featn, sev, cnt);
  // d_out doubles as 64MB aexp scratch until k_write overwrites it
  k_gemm<<<dim3(4, 64), 256, 0, stream>>>(nv1, nv2, out);
  k_row<<<NN, 256, 0, stream>>>(base, out, featn, sev, alpha, cnt, kidx, kval, dinv);
  k_write<<<NN, 256, 0, stream>>>(kidx, kval, dinv, out);
}